// Round 2
// baseline (353.233 us; speedup 1.0000x reference)
//
#include <hip/hip_runtime.h>

#define CLIPV 100000.0f
typedef __attribute__((address_space(3))) void as3void;
typedef __attribute__((address_space(1))) void as1void;

__device__ __forceinline__ float fexp2(float x) { return __builtin_amdgcn_exp2f(x); }
__device__ __forceinline__ float frcp(float x)  { return __builtin_amdgcn_rcpf(x); }

struct PP { float smax_s, qmax_s, k10, inv_smax, ddf5, tmax3, cw, Kc, cf; };

// soilbucket at state s1: qq = total drain, et = c_et*pet, o0 = qsurf+qst, o1 = qgr
__device__ __forceinline__ void soilb(float s1, const PP& P,
                                      float& qq, float& c_et, float& o0, float& o1)
{
    const float NL = -14.426950408889634f;  // -10*log2(e)
    float d   = s1 - P.smax_s;
    float eo  = fminf(fexp2(NL * d), 1e30f);
    float ep  = fminf(fexp2(NL * s1), 1e30f);
    float hpo = frcp((1.0f + ep) * (1.0f + eo));   // h_pos*h_over
    float hpu = eo * hpo;                          // h_pos*h_under
    float e   = fexp2(P.cf * d);                   // exp(-f10*(smax-s1))
    float qsub  = P.qmax_s * fmaf(hpu, e, hpo);
    float qsurf = hpo * d;
    float qst = qsub * P.k10;
    o0 = qsurf + qst;
    o1 = qsub - qst;
    qq = qsurf + qsub;
    c_et = fmaf(hpu * s1, P.inv_smax, hpo);
}

__device__ __forceinline__ void one_step(float p, float tm, float dl, const PP& P,
                                         float& s0, float& s1, float& qq, float& c_et,
                                         float& o0, float& o1)
{
    const float NL = -14.426950408889634f;
    // pet: one rcp for both denominators
    float t1v = tm + 237.3f, t2v = tm + 273.2f;
    float r12 = frcp(t1v * t2v);
    float e1  = fexp2(24.958624207f * tm * (r12 * t2v));   // exp(17.3 tm/(tm+237.3))
    float pet = 436.98720f * dl * e1 * (r12 * t1v);
    // shared exp for rain gate + melt gate; one rcp for w and hg
    float ew  = fexp2(fmaf(NL, tm, P.cw));                 // exp(-10(tm - tmin_s)), finite
    float eg  = fminf(ew * P.Kc, 1e30f);                   // exp(-10(tm - tmax3))
    float es0 = fexp2(NL * s0);                            // s0 >= 0 -> <= 1
    float Aw  = 1.0f + ew;
    float Bg  = (1.0f + es0) * (1.0f + eg);
    float tt  = frcp(Aw * Bg);                             // overflow -> 0 (correct limit)
    float w   = tt * Bg;            // heaviside(tm - tmin_s)
    float hg  = tt * Aw;            // heaviside(s0)*heaviside(tm - tmax3)
    float prain = w * p;
    float psnow = p - prain;
    float m   = hg * fminf(s0, P.ddf5 * (tm - P.tmax3));
    float et  = c_et * pet;
    float ds0 = psnow - m;
    float ds1 = prain + m - et - qq;
    s0 += fminf(fmaxf(ds0, -CLIPV), CLIPV);
    s1 += fminf(fmaxf(ds1, -CLIPV), CLIPV);
    soilb(s1, P, qq, c_et, o0, o1);   // updated s1 -> this step's outputs + next drains
}

// Tiling: 64 chains/block (1 wave), 16 steps/stage, 64 stages.
// Input LDS tile: 64 rows x 13 units(16B) [12 real (48 floats) + 1 pad]; stride 208B.
//   ds_read_b128 start banks: 52*c mod 32, gcd=4 -> conflict floor.
// Output LDS tile: 64 rows x 9 units [8 real (32 floats = 16 steps x 2) + 1 pad]; 144B.
#define WAIT_VM(N) { asm volatile("s_waitcnt vmcnt(" #N ")" ::: "memory"); \
                     __builtin_amdgcn_sched_barrier(0); }

extern "C" __global__ void __launch_bounds__(64)
prnn_kernel(const float* __restrict__ inp,
            const float* __restrict__ fpar,  const float* __restrict__ smaxp,
            const float* __restrict__ qmaxp, const float* __restrict__ ddfp,
            const float* __restrict__ tminp, const float* __restrict__ tmaxp,
            const float* __restrict__ kp,
            float* __restrict__ out)
{
    __shared__ alignas(16) unsigned char lin[2][64 * 13 * 16];  // 2 x 13312 B
    __shared__ alignas(16) unsigned char lout[64 * 9 * 16];     // 9216 B

    const int l  = threadIdx.x;
    const int c0 = blockIdx.x * 64;

    PP P;
    float f10    = fpar[0] * 0.1f;
    P.smax_s     = smaxp[0] * 1500.0f;
    P.qmax_s     = qmaxp[0] * 50.0f;
    P.ddf5       = ddfp[0] * 5.0f;
    float tmin_s = tminp[0] * -3.0f;
    P.tmax3      = tmaxp[0] * 3.0f;
    P.k10        = kp[0] * 0.1f;
    P.inv_smax   = 1.0f / P.smax_s;
    P.cw         = 14.426950408889634f * tmin_s;
    P.Kc         = fexp2(14.426950408889634f * (P.tmax3 - tmin_s));
    P.cf         = 1.4426950408889634f * f10;

    const float* gin  = inp + (size_t)c0 * 3072;   // chain rows: 3072 floats
    float*       gout = out + (size_t)c0 * 2048;   // out rows: 2048 floats

    // ---- stage loader: 13 global_load_lds (16B) into linear LDS; pad unit filled
    // from a clamped (dummy) source address so the LDS layout stays linear.
    auto stage_load = [&](int s, int pb) {
        const float* gb = gin + s * 48;
        #pragma unroll
        for (int k2 = 0; k2 < 13; ++k2) {
            unsigned e = (unsigned)(k2 * 64 + l);
            unsigned r = (e * 161321u) >> 21;       // e/13, exact for e<832
            int q = (int)(e - r * 13u);
            q = (q > 11) ? 11 : q;                  // pad unit -> dummy load
            const float* g = gb + r * 3072 + q * 4;
            __builtin_amdgcn_global_load_lds((as1void*)g,
                (as3void*)(&lin[pb][k2 * 1024]), 16, 0, 0);
        }
    };

    float s0v = 0.0f, s1v = 0.0f, qq, c_et, u0, u1;
    soilb(0.0f, P, qq, c_et, u0, u1);   // initial drain coeffs at s1=0

    auto compute_stage = [&](int pb) {
        const unsigned char* myrow = &lin[pb][l * 208];
        unsigned char*       orow  = &lout[l * 144];
        #pragma unroll
        for (int u = 0; u < 4; ++u) {
            const float4* rp = (const float4*)(myrow + u * 48);
            float4 Aq = rp[0], Bq = rp[1], Cq = rp[2];
            float o0,o1,o2,o3,o4,o5,o6,o7;
            one_step(Aq.x, Aq.y, Aq.z, P, s0v, s1v, qq, c_et, o0, o1);
            one_step(Aq.w, Bq.x, Bq.y, P, s0v, s1v, qq, c_et, o2, o3);
            one_step(Bq.z, Bq.w, Cq.x, P, s0v, s1v, qq, c_et, o4, o5);
            one_step(Cq.y, Cq.z, Cq.w, P, s0v, s1v, qq, c_et, o6, o7);
            float4* op = (float4*)(orow + u * 32);
            op[0] = make_float4(o0, o1, o2, o3);
            op[1] = make_float4(o4, o5, o6, o7);
        }
    };

    auto writeback = [&](int s) {   // 9 coalesced dwordx4 stores
        float* gb = gout + s * 32;
        #pragma unroll
        for (int k2 = 0; k2 < 9; ++k2) {
            unsigned e = (unsigned)(k2 * 64 + l);
            unsigned r = (e * 233017u) >> 21;       // e/9, exact for e<576
            int q = (int)(e - r * 9u);
            if (q < 8) {
                float4 v = *(const float4*)(&lout[e * 16]);
                *(float4*)(gb + r * 2048 + q * 4) = v;
            }
        }
    };

    // ---- prologue
    stage_load(0, 0);
    WAIT_VM(0);
    stage_load(1, 1);
    compute_stage(0);
    // ---- steady state: [wb(s-1): 9 st][load(s+1): 13 ld][wait 22][compute(s)]
    for (int s = 1; s < 63; ++s) {
        writeback(s - 1);
        stage_load(s + 1, (s + 1) & 1);
        WAIT_VM(22);          // all but {9 stores + 13 loads} retired => stage-s loads done
        compute_stage(s & 1);
    }
    // ---- tail
    writeback(62);
    WAIT_VM(9);               // stage-63 loads done (9 newer stores allowed in flight)
    compute_stage(1);         // 63 & 1
    writeback(63);
}

extern "C" void kernel_launch(void* const* d_in, const int* in_sizes, int n_in,
                              void* d_out, int out_size, void* d_ws, size_t ws_size,
                              hipStream_t stream) {
    const float* inp = (const float*)d_in[0];
    const int B = in_sizes[0] / 3072;   // T=1024, 3 features
    prnn_kernel<<<B / 64, 64, 0, stream>>>(
        inp,
        (const float*)d_in[1],  // f
        (const float*)d_in[2],  // smax
        (const float*)d_in[3],  // qmax
        (const float*)d_in[4],  // ddf
        (const float*)d_in[5],  // tmin
        (const float*)d_in[6],  // tmax
        (const float*)d_in[7],  // k
        (float*)d_out);
}

// Round 3
// 308.641 us; speedup vs baseline: 1.1445x; 1.1445x over previous
//
#include <hip/hip_runtime.h>

#define CLIPV 100000.0f
typedef __attribute__((address_space(3))) void as3void;
typedef __attribute__((address_space(1))) void as1void;

__device__ __forceinline__ float fexp2(float x){ return __builtin_amdgcn_exp2f(x); }
__device__ __forceinline__ float frcp(float x){ return __builtin_amdgcn_rcpf(x); }

#define WAIT_VM(N) { asm volatile("s_waitcnt vmcnt(" #N ")" ::: "memory"); \
                     __builtin_amdgcn_sched_barrier(0); }
#define LGKM0_BAR() { asm volatile("s_waitcnt lgkmcnt(0)" ::: "memory"); \
                      __builtin_amdgcn_s_barrier(); }

// 64 chains/block. 2 waves: wave0 = consumer (serial state chains only),
// wave1 = producer (staging, state-free math, output writeback).
// Stage = 16 steps; 64 stages; skew: producer computes stage i in slot i,
// consumer computes stage i-1 in slot i, producer flushes stage i-2 in slot i.
extern "C" __global__ void __launch_bounds__(128)
prnn_kernel(const float* __restrict__ inp,
            const float* __restrict__ fpar,  const float* __restrict__ smaxp,
            const float* __restrict__ qmaxp, const float* __restrict__ ddfp,
            const float* __restrict__ tminp, const float* __restrict__ tmaxp,
            const float* __restrict__ kp,
            float* __restrict__ out)
{
    __shared__ alignas(16) unsigned char lin[2][13312];     // input tiles (64 rows x 13 x 16B)
    __shared__ alignas(16) float prodb[2][16 * 64 * 6];     // {prain,psnow,pet,eg1,tmg,pad}
    __shared__ alignas(16) float lcons[2][16 * 65 * 2];     // {qsurf,qsub}, padded rows (65)

    const int tid = threadIdx.x;
    const int l   = tid & 63;
    const int wv  = tid >> 6;
    const int c0  = blockIdx.x * 64;

    const float NL = -14.426950408889634f;   // -10*log2(e)
    float f10    = fpar[0] * 0.1f;
    float smax_s = smaxp[0] * 1500.0f;
    float qmax_s = qmaxp[0] * 50.0f;
    float ddf5   = ddfp[0] * 5.0f;
    float tmin_s = tminp[0] * -3.0f;
    float tmax3  = tmaxp[0] * 3.0f;
    float k10    = kp[0] * 0.1f;
    float inv_smax = 1.0f / smax_s;
    float cw     = 14.426950408889634f * tmin_s;
    float Kc     = fexp2(14.426950408889634f * (tmax3 - tmin_s));
    float cf     = 1.4426950408889634f * f10;

    const float* gin  = inp + (size_t)c0 * 3072;
    float*       gout = out + (size_t)c0 * 2048;

    if (wv == 1) {
        // ================= PRODUCER =================
        auto stage_load = [&](int s, int pb) {
            const float* gb = gin + s * 48;
            #pragma unroll
            for (int k2 = 0; k2 < 13; ++k2) {
                unsigned e = (unsigned)(k2 * 64 + l);
                unsigned r = (e * 161321u) >> 21;      // e/13 (e<832)
                int q = (int)(e - r * 13u);
                q = (q > 11) ? 11 : q;                 // pad unit -> dummy
                const float* g = gb + r * 3072 + q * 4;
                __builtin_amdgcn_global_load_lds((as1void*)g,
                    (as3void*)(&lin[pb][k2 * 1024]), 16, 0, 0);
            }
        };

        auto prod_step = [&](float* pw, int u, float p, float tm, float dl) {
            float t1 = tm + 237.3f, t2 = tm + 273.2f;
            float r12 = frcp(t1 * t2);
            float e1  = fexp2(24.958624207f * tm * (r12 * t2));
            float pet = 436.9872f * dl * e1 * (r12 * t1);
            float ew  = fexp2(fmaf(NL, tm, cw));
            float w   = frcp(1.0f + ew);
            float prain = w * p;
            float psnow = p - prain;
            float eg1 = 1.0f + fminf(ew * Kc, 1e30f);
            float tmg = ddf5 * (tm - tmax3);
            float* o = pw + u * 384 + l * 6;
            *(float2*)(o)     = make_float2(prain, psnow);
            *(float2*)(o + 2) = make_float2(pet, eg1);
            o[4] = tmg;
        };

        auto prod_compute = [&](int s) {
            const unsigned char* myrow = &lin[s & 1][l * 208];
            float* pw = prodb[s & 1];
            #pragma unroll
            for (int u4 = 0; u4 < 4; ++u4) {
                float4 A = *(const float4*)(myrow + u4 * 48);
                float4 B = *(const float4*)(myrow + u4 * 48 + 16);
                float4 C = *(const float4*)(myrow + u4 * 48 + 32);
                prod_step(pw, u4 * 4 + 0, A.x, A.y, A.z);
                prod_step(pw, u4 * 4 + 1, A.w, B.x, B.y);
                prod_step(pw, u4 * 4 + 2, B.z, B.w, C.x);
                prod_step(pw, u4 * 4 + 3, C.y, C.z, C.w);
            }
        };

        auto writeback = [&](int s) {
            float* gb = gout + s * 32;
            const float* lc = lcons[s & 1];
            #pragma unroll
            for (int k2 = 0; k2 < 9; ++k2) {
                unsigned e = (unsigned)(k2 * 64 + l);
                unsigned r = (e * 233017u) >> 21;      // e/9 (e<576)
                int q = (int)(e - r * 9u);
                if (q < 8) {
                    const float* p0 = lc + (2 * q) * 130 + r * 2;
                    float2 a = *(const float2*)(p0);
                    float2 b = *(const float2*)(p0 + 130);
                    float aqst = a.y * k10, bqst = b.y * k10;
                    float4 v = make_float4(a.x + aqst, a.y - aqst,
                                           b.x + bqst, b.y - bqst);
                    *(float4*)(gb + r * 2048 + q * 4) = v;
                }
            }
        };

        // slot 0
        stage_load(0, 0);
        WAIT_VM(0);
        stage_load(1, 1);
        prod_compute(0);
        LGKM0_BAR();
        // slot 1
        stage_load(2, 0);
        WAIT_VM(13);
        prod_compute(1);
        LGKM0_BAR();
        // slots 2..62
        for (int i = 2; i <= 62; ++i) {
            writeback(i - 2);
            stage_load(i + 1, (i + 1) & 1);
            WAIT_VM(22);
            prod_compute(i);
            LGKM0_BAR();
        }
        // slot 63
        writeback(61);
        WAIT_VM(9);
        prod_compute(63);
        LGKM0_BAR();
        // slot 64
        writeback(62);
        LGKM0_BAR();
        // slot 65
        writeback(63);
    } else {
        // ================= CONSUMER =================
        float s0v = 0.0f, s1v = 0.0f, qq, c_et;
        {   // soilb(0): initial drain coefficients
            float d  = -smax_s;
            float eo = fminf(fexp2(NL * d), 1e30f);
            float ep = 1.0f;                            // exp2(0)
            float hpo = frcp((1.0f + ep) * (1.0f + eo));
            float hpu = eo * hpo;
            float e   = fexp2(cf * d);
            float qsub  = qmax_s * fmaf(hpu, e, hpo);
            float qsurf = hpo * d;
            qq   = qsurf + qsub;
            c_et = fmaf(hpu * 0.0f, inv_smax, hpo);
        }
        LGKM0_BAR();                                    // slot 0 (idle)
        for (int i = 1; i <= 64; ++i) {
            const int s = i - 1;
            const float* pr = prodb[s & 1];
            float* lc = lcons[s & 1];
            #pragma unroll
            for (int u = 0; u < 16; ++u) {
                const float* pb = pr + u * 384 + l * 6;
                float2 v0 = *(const float2*)(pb);       // prain, psnow
                float2 v1 = *(const float2*)(pb + 2);   // pet, eg1
                float tmg = pb[4];
                float es0 = fexp2(NL * s0v);
                float hg  = frcp((1.0f + es0) * v1.y);
                float m   = hg * fminf(s0v, tmg);
                float et  = c_et * v1.x;
                float ds0 = v0.y - m;
                float ds1 = v0.x + m - et - qq;
                s0v += fminf(fmaxf(ds0, -CLIPV), CLIPV);
                s1v += fminf(fmaxf(ds1, -CLIPV), CLIPV);
                float d   = s1v - smax_s;
                float eo  = fminf(fexp2(NL * d), 1e30f);
                float ep  = fminf(fexp2(NL * s1v), 1e30f);
                float hpo = frcp((1.0f + ep) * (1.0f + eo));
                float hpu = eo * hpo;
                float e   = fexp2(cf * d);
                float qsub  = qmax_s * fmaf(hpu, e, hpo);
                float qsurf = hpo * d;
                qq   = qsurf + qsub;
                c_et = fmaf(hpu * s1v, inv_smax, hpo);
                *(float2*)(lc + u * 130 + l * 2) = make_float2(qsurf, qsub);
            }
            LGKM0_BAR();
        }
    }
}

extern "C" void kernel_launch(void* const* d_in, const int* in_sizes, int n_in,
                              void* d_out, int out_size, void* d_ws, size_t ws_size,
                              hipStream_t stream) {
    const float* inp = (const float*)d_in[0];
    const int B = in_sizes[0] / 3072;   // T=1024, 3 features
    prnn_kernel<<<B / 64, 128, 0, stream>>>(
        inp,
        (const float*)d_in[1],  // f
        (const float*)d_in[2],  // smax
        (const float*)d_in[3],  // qmax
        (const float*)d_in[4],  // ddf
        (const float*)d_in[5],  // tmin
        (const float*)d_in[6],  // tmax
        (const float*)d_in[7],  // k
        (float*)d_out);
}

// Round 6
// 304.077 us; speedup vs baseline: 1.1617x; 1.0150x over previous
//
#include <hip/hip_runtime.h>

#define CLIPV 100000.0f
typedef __attribute__((address_space(3))) void as3void;
typedef __attribute__((address_space(1))) void as1void;

__device__ __forceinline__ float fexp2(float x){ return __builtin_amdgcn_exp2f(x); }
__device__ __forceinline__ float frcp(float x){ return __builtin_amdgcn_rcpf(x); }

#define WAIT_VM(N) { asm volatile("s_waitcnt vmcnt(" #N ")" ::: "memory"); \
                     __builtin_amdgcn_sched_barrier(0); }
#define LGKM0_BAR() { asm volatile("s_waitcnt lgkmcnt(0)" ::: "memory"); \
                      __builtin_amdgcn_s_barrier(); }

// 64 chains/block, 2 waves.
// wave0 = consumer: the serial recurrence, PURE-REGISTER per step
//   (one 20x ds_read_b128 burst per 16-step slot, 8x ds_write_b128 out).
// wave1 = producer: global->LDS staging, state-free per-step math, writeback.
// prodb lane row (84 floats = 336B = 21*16B): [q][16] q = {prain,psnow,pet,eg1,tmg}
// lcons lane row (36 floats = 144B):          [q][16] q = {qq, qsub}
extern "C" __global__ void __launch_bounds__(128, 1)
prnn_kernel(const float* __restrict__ inp,
            const float* __restrict__ fpar,  const float* __restrict__ smaxp,
            const float* __restrict__ qmaxp, const float* __restrict__ ddfp,
            const float* __restrict__ tminp, const float* __restrict__ tmaxp,
            const float* __restrict__ kp,
            float* __restrict__ out)
{
    __shared__ alignas(16) unsigned char lin[2][13312];   // 64 rows x 13 x 16B
    __shared__ alignas(16) float prodb[2][64 * 84];       // 2 x 21504 B
    __shared__ alignas(16) float lcons[2][64 * 36];       // 2 x 9216 B

    const int tid = threadIdx.x;
    const int l   = tid & 63;
    const int wv  = tid >> 6;
    const int c0  = blockIdx.x * 64;

    const float NL = -14.426950408889634f;   // -10*log2(e)
    float f10    = fpar[0] * 0.1f;
    float smax_s = smaxp[0] * 1500.0f;
    float qmax_s = qmaxp[0] * 50.0f;
    float ddf5   = ddfp[0] * 5.0f;
    float tmin_s = tminp[0] * -3.0f;
    float tmax3  = tmaxp[0] * 3.0f;
    float k10    = kp[0] * 0.1f;
    float ism    = 1.0f / smax_s;
    float cw     = 14.426950408889634f * tmin_s;
    float Kc     = fexp2(14.426950408889634f * (tmax3 - tmin_s));
    float cf     = 1.4426950408889634f * f10;
    float k1m    = 1.0f - k10;

    const float* gin  = inp + (size_t)c0 * 3072;
    float*       gout = out + (size_t)c0 * 2048;

    if (wv == 1) {
        // ================= PRODUCER =================
        auto stage_load = [&](int s, int pb) {
            const float* gb = gin + s * 48;
            #pragma unroll
            for (int k2 = 0; k2 < 13; ++k2) {
                unsigned e = (unsigned)(k2 * 64 + l);
                unsigned r = (e * 161321u) >> 21;      // e/13 (e<832)
                int q = (int)(e - r * 13u);
                q = (q > 11) ? 11 : q;                 // pad unit -> dummy
                const float* g = gb + r * 3072 + q * 4;
                __builtin_amdgcn_global_load_lds((as1void*)g,
                    (as3void*)(&lin[pb][k2 * 1024]), 16, 0, 0);
            }
        };

        auto prod_one = [&](float p, float tm, float dl,
                            float& pr, float& ps, float& pe, float& eg, float& tg) {
            float t1 = tm + 237.3f, t2 = tm + 273.2f;
            float r12 = frcp(t1 * t2);
            float e1  = fexp2(24.958624207f * tm * (r12 * t2));
            pe = 436.9872f * dl * e1 * (r12 * t1);
            float ew = fexp2(fmaf(NL, tm, cw));        // exp(-10(tm - tmin_s))
            float w  = frcp(1.0f + ew);
            pr = w * p;
            ps = p - pr;
            eg = 1.0f + fminf(ew * Kc, 1e30f);         // 1 + exp(-10(tm - tmax3))
            tg = ddf5 * (tm - tmax3);
        };

        auto prod_compute = [&](int s) {
            const unsigned char* myrow = &lin[s & 1][l * 208];
            float* o = prodb[s & 1] + l * 84;
            #pragma unroll
            for (int u4 = 0; u4 < 4; ++u4) {
                float4 A = *(const float4*)(myrow + u4 * 48);
                float4 B = *(const float4*)(myrow + u4 * 48 + 16);
                float4 C = *(const float4*)(myrow + u4 * 48 + 32);
                float pr[4], ps[4], pe[4], eg[4], tg[4];
                prod_one(A.x, A.y, A.z, pr[0], ps[0], pe[0], eg[0], tg[0]);
                prod_one(A.w, B.x, B.y, pr[1], ps[1], pe[1], eg[1], tg[1]);
                prod_one(B.z, B.w, C.x, pr[2], ps[2], pe[2], eg[2], tg[2]);
                prod_one(C.y, C.z, C.w, pr[3], ps[3], pe[3], eg[3], tg[3]);
                *(float4*)(o +      u4 * 4) = make_float4(pr[0], pr[1], pr[2], pr[3]);
                *(float4*)(o + 16 + u4 * 4) = make_float4(ps[0], ps[1], ps[2], ps[3]);
                *(float4*)(o + 32 + u4 * 4) = make_float4(pe[0], pe[1], pe[2], pe[3]);
                *(float4*)(o + 48 + u4 * 4) = make_float4(eg[0], eg[1], eg[2], eg[3]);
                *(float4*)(o + 64 + u4 * 4) = make_float4(tg[0], tg[1], tg[2], tg[3]);
            }
        };

        auto writeback = [&](int s) {
            float* gb = gout + s * 32;
            const float* lc = lcons[s & 1];
            #pragma unroll
            for (int k2 = 0; k2 < 9; ++k2) {
                unsigned e = (unsigned)(k2 * 64 + l);
                unsigned r = (e * 233017u) >> 21;      // e/9 (e<576)
                int q = (int)(e - r * 9u);
                if (q < 8) {
                    const float* p0 = lc + r * 36 + 2 * q;       // qq[2q..2q+1]
                    float2 qqv = *(const float2*)(p0);
                    float2 qbv = *(const float2*)(p0 + 16);      // qsub[2q..2q+1]
                    float o1a = k1m * qbv.x, o1b = k1m * qbv.y;
                    float4 v = make_float4(qqv.x - o1a, o1a, qqv.y - o1b, o1b);
                    *(float4*)(gb + r * 2048 + q * 4) = v;
                }
            }
        };

        // slot 0
        stage_load(0, 0);
        WAIT_VM(0);
        stage_load(1, 1);
        prod_compute(0);
        LGKM0_BAR();
        // slot 1
        stage_load(2, 0);
        WAIT_VM(13);
        prod_compute(1);
        LGKM0_BAR();
        // slots 2..62
        for (int i = 2; i <= 62; ++i) {
            writeback(i - 2);
            stage_load(i + 1, (i + 1) & 1);
            WAIT_VM(22);
            prod_compute(i);
            LGKM0_BAR();
        }
        // slot 63
        writeback(61);
        WAIT_VM(9);
        prod_compute(63);
        LGKM0_BAR();
        // slot 64
        writeback(62);
        LGKM0_BAR();
        // slot 65
        writeback(63);
    } else {
        // ================= CONSUMER (pure-register recurrence) =================
        float s0v = 0.0f, s1v = 0.0f, qq, c_et;
        {   // soilb(0): initial drain coefficients (refactored form)
            float d   = -smax_s;
            float eo  = fminf(fexp2(NL * d), 1e30f);
            float ep  = 1.0f;
            float den = (1.0f + ep) * (1.0f + eo);
            float hpo = frcp(den);
            float e   = fexp2(cf * d);
            float w1  = fmaf(e, eo, 1.0f);
            qq   = hpo * fmaf(qmax_s, w1, d);
            c_et = hpo;                         // fma(eo, s1*ism, 1)*hpo at s1=0 -> hpo
        }
        LGKM0_BAR();                            // slot 0 (producer fills stage 0)

        for (int i = 1; i <= 64; ++i) {
            const int sb = (i - 1) & 1;
            const float* base = prodb[sb] + l * 84;
            float4 PR[5][4];
            #pragma unroll
            for (int q = 0; q < 5; ++q) {
                #pragma unroll
                for (int g = 0; g < 4; ++g)
                    PR[q][g] = *(const float4*)(base + q * 16 + g * 4);
            }
            float* lcb = lcons[sb] + l * 36;

            auto STEP = [&](float prain, float psnow, float pet, float eg1, float tmg,
                            float& oqq, float& oqb) {
                // s0 chain
                float es0 = fexp2(NL * s0v);
                float hg  = frcp(fmaf(es0, eg1, eg1));      // h(s0)*h(t-tmax3)
                float m   = hg * fminf(s0v, tmg);
                float ds0 = psnow - m;
                s0v += fminf(fmaxf(ds0, -CLIPV), CLIPV);
                // s1 chain
                float et  = c_et * pet;
                float pme = (prain + m) - et;
                float ds1 = pme - qq;
                s1v += fminf(fmaxf(ds1, -CLIPV), CLIPV);
                // soilbucket at updated s1 (outputs + next drains)
                float d   = s1v - smax_s;
                float eo  = fminf(fexp2(NL * d), 1e30f);
                float e   = fexp2(cf * d);
                float ep  = fminf(fexp2(NL * s1v), 1e30f);
                float den = (1.0f + ep) * (1.0f + eo);
                float hpo = frcp(den);
                float w1  = fmaf(e, eo, 1.0f);
                float qmw = qmax_s * w1;
                qq   = hpo * (d + qmw);
                oqb  = hpo * qmw;                           // qsub
                oqq  = qq;
                c_et = hpo * fmaf(eo, s1v * ism, 1.0f);
            };

            #pragma unroll
            for (int g = 0; g < 4; ++g) {
                float qs[4], qb[4];
                STEP(PR[0][g].x, PR[1][g].x, PR[2][g].x, PR[3][g].x, PR[4][g].x, qs[0], qb[0]);
                STEP(PR[0][g].y, PR[1][g].y, PR[2][g].y, PR[3][g].y, PR[4][g].y, qs[1], qb[1]);
                STEP(PR[0][g].z, PR[1][g].z, PR[2][g].z, PR[3][g].z, PR[4][g].z, qs[2], qb[2]);
                STEP(PR[0][g].w, PR[1][g].w, PR[2][g].w, PR[3][g].w, PR[4][g].w, qs[3], qb[3]);
                *(float4*)(lcb +      g * 4) = make_float4(qs[0], qs[1], qs[2], qs[3]);
                *(float4*)(lcb + 16 + g * 4) = make_float4(qb[0], qb[1], qb[2], qb[3]);
            }
            LGKM0_BAR();
        }
    }
}

extern "C" void kernel_launch(void* const* d_in, const int* in_sizes, int n_in,
                              void* d_out, int out_size, void* d_ws, size_t ws_size,
                              hipStream_t stream) {
    const float* inp = (const float*)d_in[0];
    const int B = in_sizes[0] / 3072;   // T=1024, 3 features
    prnn_kernel<<<B / 64, 128, 0, stream>>>(
        inp,
        (const float*)d_in[1],  // f
        (const float*)d_in[2],  // smax
        (const float*)d_in[3],  // qmax
        (const float*)d_in[4],  // ddf
        (const float*)d_in[5],  // tmin
        (const float*)d_in[6],  // tmax
        (const float*)d_in[7],  // k
        (float*)d_out);
}